// Round 1
// 455.033 us; speedup vs baseline: 1.1508x; 1.1508x over previous
//
#include <hip/hip_runtime.h>

// Attention_25855703122265: B=2, S=2048, D=2048, H=16, hd=128, causal prefill.
// fp32 I/O; bf16 MFMA compute.
//
// Round 6 (this round):
//  - gemm_qkv also writes bf16 K copy (kb_ws); new trans_v pass writes bf16
//    V^T [B,H,128,S] (vt_ws).
//  - attn_fwd v3: 512 threads (8 waves x 16 q-rows), K and V^T staged via
//    global_load_lds(16B) with XOR chunk swizzle (linear LDS dest,
//    pre-swizzled global source, swizzled ds_read) -> zero staging VALU,
//    2-way (free) bank conflicts. 3 barriers/iter. 256 pair-balanced blocks
//    (17 K-iters each), 2 waves/SIMD.
//
// Memory map:
//  d_out (fp32): a [0,8.39M) | k present [8.39M,16.78M) | v [16.78M,25.17M)
//    a-region reused as scratch until proj: xb bf16 @ bytes [0,16.78M),
//    q bf16 @ bytes [16.78M,33.55M)  (dead before proj GEMM writes a).
//  d_ws (83.9 MB): wt_q|wt_k|wt_v|wt_d (bf16 [N,K], 8.39MB each)
//    | attn_ws bf16 16.78MB | kb_ws bf16 16.78MB | vt_ws bf16 16.78MB

typedef unsigned short ushort_t;
typedef __attribute__((ext_vector_type(8))) short short8;   // 8 x bf16
typedef __attribute__((ext_vector_type(4))) float f32x4;

#define MFMA16x16x32 __builtin_amdgcn_mfma_f32_16x16x32_bf16
#define S_LEN   2048
#define DMODEL  2048
#define A_ELEMS 8388608   // B*S*D
#define W_ELEMS 4194304   // D*D

__device__ __forceinline__ ushort_t f2bf(float x) {
  unsigned u = __float_as_uint(x);
  u += 0x7FFFu + ((u >> 16) & 1u);
  return (ushort_t)(u >> 16);
}
__device__ __forceinline__ unsigned pack2(float lo, float hi) {
  return (unsigned)f2bf(lo) | ((unsigned)f2bf(hi) << 16);
}
struct f8 { float v[8]; };
__device__ __forceinline__ f8 ld8f(const float* p) {
  f8 r;
  float4 a = *(const float4*)p, b = *(const float4*)(p + 4);
  r.v[0]=a.x; r.v[1]=a.y; r.v[2]=a.z; r.v[3]=a.w;
  r.v[4]=b.x; r.v[5]=b.y; r.v[6]=b.z; r.v[7]=b.w;
  return r;
}
__device__ __forceinline__ uint4 cvt8(const f8& f) {
  uint4 o;
  o.x = pack2(f.v[0], f.v[1]); o.y = pack2(f.v[2], f.v[3]);
  o.z = pack2(f.v[4], f.v[5]); o.w = pack2(f.v[6], f.v[7]);
  return o;
}

// async global->LDS, 16B/lane; dest = wave-uniform base + lane*16
typedef const __attribute__((address_space(1))) void* gas_t;
typedef __attribute__((address_space(3))) void* las_t;
__device__ __forceinline__ void gld16(const void* g, void* l) {
  __builtin_amdgcn_global_load_lds((gas_t)(unsigned long long)g,
                                   (las_t)(unsigned)(unsigned long long)l,
                                   16, 0, 0);
}

// ---------------------------------------------------------------------------
// Prepass 1: x fp32 -> xb bf16 (straight convert, 8 elems/thread)
// ---------------------------------------------------------------------------
__global__ void __launch_bounds__(256) conv_x(const float* __restrict__ x,
                                              ushort_t* __restrict__ xb) {
  const int i = (blockIdx.x * 256 + threadIdx.x) * 8;
  f8 v = ld8f(x + i);
  *(uint4*)&xb[i] = cvt8(v);
}

// ---------------------------------------------------------------------------
// Prepass 2: W fp32 [K,N] -> wt bf16 [N,K]; 64x64 tiles; z picks weight
// ---------------------------------------------------------------------------
__global__ void __launch_bounds__(256) trans_w(
    const float* __restrict__ w0, const float* __restrict__ w1,
    const float* __restrict__ w2, const float* __restrict__ w3,
    ushort_t* __restrict__ o0, ushort_t* __restrict__ o1,
    ushort_t* __restrict__ o2, ushort_t* __restrict__ o3) {
  __shared__ float t[64][65];
  const float* src; ushort_t* dst;
  switch (blockIdx.z) {
    case 0: src = w0; dst = o0; break;
    case 1: src = w1; dst = o1; break;
    case 2: src = w2; dst = o2; break;
    default: src = w3; dst = o3; break;
  }
  const int kb = blockIdx.y * 64, nb = blockIdx.x * 64;
  const int r = threadIdx.x >> 3, c8 = (threadIdx.x & 7) * 8;
#pragma unroll
  for (int i = 0; i < 64; i += 32) {
    *(float4*)&t[r + i][c8]     = *(const float4*)&src[(size_t)(kb + r + i) * DMODEL + nb + c8];
    *(float4*)&t[r + i][c8 + 4] = *(const float4*)&src[(size_t)(kb + r + i) * DMODEL + nb + c8 + 4];
  }
  __syncthreads();
#pragma unroll
  for (int i = 0; i < 64; i += 32) {
    float tmp[8];
#pragma unroll
    for (int j = 0; j < 8; ++j) tmp[j] = t[c8 + j][r + i];
    uint4 o;
    o.x = pack2(tmp[0], tmp[1]); o.y = pack2(tmp[2], tmp[3]);
    o.z = pack2(tmp[4], tmp[5]); o.w = pack2(tmp[6], tmp[7]);
    *(uint4*)&dst[(size_t)(nb + r + i) * DMODEL + kb + c8] = o;
  }
}

// ---------------------------------------------------------------------------
// Prepass 3 (after gemm_qkv): v fp32 [B,H,S,128] -> vt bf16 [B,H,128,S]
// 64x64 tiles, same structure as trans_w.
// ---------------------------------------------------------------------------
__global__ void __launch_bounds__(256) trans_v(const float* __restrict__ v,
                                               ushort_t* __restrict__ vt) {
  __shared__ float t[64][65];
  const int bh = blockIdx.z;
  const int sb = blockIdx.x * 64, db = blockIdx.y * 64;
  const float* src = v + (size_t)bh * S_LEN * 128;
  ushort_t* dst = vt + (size_t)bh * 128 * S_LEN;
  const int r = threadIdx.x >> 3, c8 = (threadIdx.x & 7) * 8;
#pragma unroll
  for (int i = 0; i < 64; i += 32) {
    *(float4*)&t[r + i][c8]     = *(const float4*)&src[(size_t)(sb + r + i) * 128 + db + c8];
    *(float4*)&t[r + i][c8 + 4] = *(const float4*)&src[(size_t)(sb + r + i) * 128 + db + c8 + 4];
  }
  __syncthreads();
#pragma unroll
  for (int i = 0; i < 64; i += 32) {
    float tmp[8];
#pragma unroll
    for (int j = 0; j < 8; ++j) tmp[j] = t[c8 + j][r + i];
    uint4 o;
    o.x = pack2(tmp[0], tmp[1]); o.y = pack2(tmp[2], tmp[3]);
    o.z = pack2(tmp[4], tmp[5]); o.w = pack2(tmp[6], tmp[7]);
    *(uint4*)&dst[(size_t)(db + r + i) * S_LEN + sb + c8] = o;
  }
}

// ---------------------------------------------------------------------------
// Shared GEMM core: acc[4][4] += A128x32 @ Bt128x32^T over K=2048 (m97-style)
// ---------------------------------------------------------------------------
__device__ __forceinline__ void gemm_core(
    const ushort_t* __restrict__ gA, const ushort_t* __restrict__ gB,
    ushort_t* As, ushort_t* Bs, int w, int lane, int wr, int wc,
    f32x4 acc[4][4]) {
  const int sr = lane >> 2, sc = (lane & 3) * 8;
  const int l15 = lane & 15, quad = lane >> 4;
  const ushort_t* pA = gA + sc;
  const ushort_t* pB = gB + sc;
  for (int kt = 0; kt < 2048; kt += 32) {
    __syncthreads();
#pragma unroll
    for (int i = 0; i < 4; ++i) {
      const int c = i * 4 + w;  // wave-uniform chunk (16 rows x 32 cols = 1KB)
      if (c < 8)
        gld16(pA + (size_t)(c * 16 + sr) * 2048 + kt, (void*)(As + c * 512));
      else
        gld16(pB + (size_t)((c - 8) * 16 + sr) * 2048 + kt,
              (void*)(Bs + (c - 8) * 512));
    }
    __syncthreads();
    short8 af[4], bf[4];
#pragma unroll
    for (int mi = 0; mi < 4; ++mi)
      af[mi] = *(const short8*)&As[(wr + mi * 16 + l15) * 32 + quad * 8];
#pragma unroll
    for (int ni = 0; ni < 4; ++ni)
      bf[ni] = *(const short8*)&Bs[(wc + ni * 16 + l15) * 32 + quad * 8];
#pragma unroll
    for (int mi = 0; mi < 4; ++mi)
#pragma unroll
      for (int ni = 0; ni < 4; ++ni)
        acc[mi][ni] = MFMA16x16x32(af[mi], bf[ni], acc[mi][ni], 0, 0, 0);
  }
}

// ---------------------------------------------------------------------------
// Fused QKV GEMM: wid = bx>>9 picks {q,k,v}. q -> bf16 scatter [B,H,S,hd];
// k -> fp32 scatter + bf16 copy; v -> fp32 scatter.
// ---------------------------------------------------------------------------
__global__ void __launch_bounds__(256) gemm_qkv(
    const ushort_t* __restrict__ xb,
    const ushort_t* __restrict__ wtq, const ushort_t* __restrict__ wtk,
    const ushort_t* __restrict__ wtv,
    const float* __restrict__ bq, const float* __restrict__ bk,
    const float* __restrict__ bv,
    ushort_t* __restrict__ qout, float* __restrict__ kout,
    float* __restrict__ vout, ushort_t* __restrict__ kb16) {
  __shared__ ushort_t As[4096], Bs[4096];
  const int tid = threadIdx.x, w = tid >> 6, lane = tid & 63;
  const int l15 = lane & 15, quad = lane >> 4;
  const int bx = blockIdx.x, wid = bx >> 9, r = bx & 511;
  const int tm = r & 31, tn = r >> 5;
  const int wr = (w >> 1) * 64, wc = (w & 1) * 64;
  const ushort_t* Wt = wid == 0 ? wtq : (wid == 1 ? wtk : wtv);
  const float* bias = wid == 0 ? bq : (wid == 1 ? bk : bv);

  f32x4 acc[4][4] = {};
  gemm_core(xb + (size_t)(tm * 128) * 2048, Wt + (size_t)(tn * 128) * 2048,
            As, Bs, w, lane, wr, wc, acc);

  const int row0 = tm * 128 + wr, col0 = tn * 128 + wc;
#pragma unroll
  for (int ni = 0; ni < 4; ++ni) {
    const int col = col0 + ni * 16 + l15;
    const float bv_ = bias[col];
    const int h = col >> 7, d = col & 127;
#pragma unroll
    for (int mi = 0; mi < 4; ++mi) {
#pragma unroll
      for (int j = 0; j < 4; ++j) {
        const int row = row0 + mi * 16 + quad * 4 + j;
        const int b = row >> 11, s = row & 2047;
        const size_t idx = (size_t)(((b * 16 + h) * 2048 + s)) * 128 + d;
        const float v = acc[mi][ni][j] + bv_;
        if (wid == 0) qout[idx] = f2bf(v);
        else if (wid == 1) { kout[idx] = v; kb16[idx] = f2bf(v); }
        else vout[idx] = v;
      }
    }
  }
}

// ---------------------------------------------------------------------------
// Proj GEMM: a[4096,2048] fp32 = attn_ws bf16 @ wt_d^T + bd
// ---------------------------------------------------------------------------
__global__ void __launch_bounds__(256) gemm_proj(
    const ushort_t* __restrict__ A, const ushort_t* __restrict__ Wt,
    const float* __restrict__ bias, float* __restrict__ C) {
  __shared__ ushort_t As[4096], Bs[4096];
  const int tid = threadIdx.x, w = tid >> 6, lane = tid & 63;
  const int l15 = lane & 15, quad = lane >> 4;
  const int tm = blockIdx.x & 31, tn = blockIdx.x >> 5;
  const int wr = (w >> 1) * 64, wc = (w & 1) * 64;

  f32x4 acc[4][4] = {};
  gemm_core(A + (size_t)(tm * 128) * 2048, Wt + (size_t)(tn * 128) * 2048,
            As, Bs, w, lane, wr, wc, acc);

  const int row0 = tm * 128 + wr, col0 = tn * 128 + wc;
#pragma unroll
  for (int ni = 0; ni < 4; ++ni) {
    const int col = col0 + ni * 16 + l15;
    const float bv_ = bias[col];
#pragma unroll
    for (int mi = 0; mi < 4; ++mi)
#pragma unroll
      for (int j = 0; j < 4; ++j) {
        const int row = row0 + mi * 16 + quad * 4 + j;
        C[(size_t)row * DMODEL + col] = acc[mi][ni][j] + bv_;
      }
  }
}

// ---------------------------------------------------------------------------
// Flash causal attention v3. 256 blocks x 512 threads (8 waves x 16 q-rows).
// Block bx: bh = bx&31, pr = bx>>5; q-tiles {15-pr, pr} -> 17 K-iters each.
// K tile and V^T tile staged via gld16 into LINEAR LDS with XOR chunk
// swizzle: LDS[row][slot s] = global[row][chunk s ^ (row&7)] (16B chunks);
// read side applies the same XOR (row&7 == l15&7 since tile rows are x16).
// Ps [128][136] aliases the K buffer after QK^T (wave-private rows).
// LDS: KP 34816B + Vs 32768B = 66KB.
// ---------------------------------------------------------------------------
__global__ void __launch_bounds__(512, 2) attn_fwd(
    const ushort_t* __restrict__ Q, const ushort_t* __restrict__ Kb,
    const ushort_t* __restrict__ Vt, ushort_t* __restrict__ O) {
  __shared__ ushort_t KP[128 * 136];  // K tile [key][d] (linear 128x128) / Ps
  __shared__ ushort_t Vs[128 * 128];  // V^T tile [d][key] (linear, swizzled)
  const int tid = threadIdx.x;
  const int w = tid >> 6, lane = tid & 63;
  const int l15 = lane & 15, quad = lane >> 4;
  const int x7 = l15 & 7;                   // read-side swizzle term
  const int bh = blockIdx.x & 31, pr = blockIdx.x >> 5;
  const int b = bh >> 4, h = bh & 15;
  const size_t base  = (size_t)bh * (S_LEN * 128);  // Q,Kb: [bh][s][128]
  const size_t vbase = (size_t)bh * (128 * S_LEN);  // Vt:   [bh][d][s]
  const float cs = 0.08838834764831845f * 1.4426950408889634f;  // 1/sqrt(128)*log2(e)

  const int srow = lane >> 4;     // staging: row within 4-row group
  const int schunk = lane & 15;   // staging: 16B slot within 256B row

  for (int seg = 0; seg < 2; ++seg) {
    const int qt = (seg == 0) ? (15 - pr) : pr;
    const int q0 = qt * 128 + w * 16;   // this wave's first q row

    // Q fragments: A-layout A[m=l15][k=quad*8+j]
    short8 qf[4];
#pragma unroll
    for (int ks = 0; ks < 4; ++ks)
      qf[ks] = *(const short8*)&Q[base + (size_t)(q0 + l15) * 128 + ks * 32 + quad * 8];

    f32x4 oacc[8] = {};
    float mrun[4], lrun[4];
#pragma unroll
    for (int j = 0; j < 4; ++j) { mrun[j] = -1e30f; lrun[j] = 0.f; }

    for (int kt = 0; kt <= qt; ++kt) {
      const int kb_ = kt * 128;
      __syncthreads();  // prev iter's Ps/Vs reads done; buffers free
      // stage K rows [w*16,w*16+16) and V^T rows same, 4 rows per gld16 call
#pragma unroll
      for (int i = 0; i < 4; ++i) {
        const int r = w * 16 + i * 4 + srow;
        const int c = schunk ^ (r & 7);           // pre-swizzled source chunk
        gld16(Kb + base + (size_t)(kb_ + r) * 128 + c * 8,
              (void*)(KP + (w * 16 + i * 4) * 128));
        gld16(Vt + vbase + (size_t)r * S_LEN + kb_ + c * 8,
              (void*)(Vs + (w * 16 + i * 4) * 128));
      }
      __syncthreads();  // drains vmcnt; staged data ready

      // S = Q K^T over 128 keys
      f32x4 sacc[8] = {};
#pragma unroll
      for (int ks = 0; ks < 4; ++ks) {
        const int sw = ((ks * 4 + quad) ^ x7) * 8;  // swizzled chunk offset
        short8 kf[8];
#pragma unroll
        for (int ni = 0; ni < 8; ++ni)
          kf[ni] = *(const short8*)&KP[(ni * 16 + l15) * 128 + sw];
#pragma unroll
        for (int ni = 0; ni < 8; ++ni)
          sacc[ni] = MFMA16x16x32(qf[ks], kf[ni], sacc[ni], 0, 0, 0);
      }
      __syncthreads();  // all kf reads done; KP becomes Ps [128][136]

      // online softmax: lane holds rows quad*4+j, cols ni*16+l15
#pragma unroll
      for (int j = 0; j < 4; ++j) {
        const int rl = quad * 4 + j;
        const int rowg = q0 + rl;
        float t0[8];
#pragma unroll
        for (int ni = 0; ni < 8; ++ni) {
          const int kg = kb_ + ni * 16 + l15;
          const float s = sacc[ni][j] * cs;
          t0[ni] = (kg <= rowg) ? s : -1e30f;
        }
        float rm = fmaxf(fmaxf(fmaxf(t0[0], t0[1]), fmaxf(t0[2], t0[3])),
                         fmaxf(fmaxf(t0[4], t0[5]), fmaxf(t0[6], t0[7])));
        rm = fmaxf(rm, __shfl_xor(rm, 1));
        rm = fmaxf(rm, __shfl_xor(rm, 2));
        rm = fmaxf(rm, __shfl_xor(rm, 4));
        rm = fmaxf(rm, __shfl_xor(rm, 8));
        const float mold = mrun[j];
        const float mnew = fmaxf(mold, rm);
        const float alpha = __builtin_amdgcn_exp2f(mold - mnew);
        float rs = 0.f;
#pragma unroll
        for (int ni = 0; ni < 8; ++ni) {
          const float pe = __builtin_amdgcn_exp2f(t0[ni] - mnew);
          rs += pe;
          KP[(w * 16 + rl) * 136 + ni * 16 + l15] = f2bf(pe);  // Ps
        }
        rs += __shfl_xor(rs, 1);
        rs += __shfl_xor(rs, 2);
        rs += __shfl_xor(rs, 4);
        rs += __shfl_xor(rs, 8);
        lrun[j] = lrun[j] * alpha + rs;
        mrun[j] = mnew;
#pragma unroll
        for (int oi = 0; oi < 8; ++oi) oacc[oi][j] *= alpha;
      }

      // O += P V  (Ps rows wave-private -> no barrier; Vs valid till next stage)
#pragma unroll
      for (int ks = 0; ks < 4; ++ks) {
        const int sw = ((ks * 4 + quad) ^ x7) * 8;
        short8 pf = *(const short8*)&KP[(w * 16 + l15) * 136 + ks * 32 + quad * 8];
        short8 vf[8];
#pragma unroll
        for (int oi = 0; oi < 8; ++oi)
          vf[oi] = *(const short8*)&Vs[(oi * 16 + l15) * 128 + sw];
#pragma unroll
        for (int oi = 0; oi < 8; ++oi)
          oacc[oi] = MFMA16x16x32(pf, vf[oi], oacc[oi], 0, 0, 0);
      }
    }

    // epilogue: O /= l, write merged-heads bf16 [B,S,D]
    {
      float inv[4];
#pragma unroll
      for (int j = 0; j < 4; ++j) inv[j] = 1.f / lrun[j];
#pragma unroll
      for (int oi = 0; oi < 8; ++oi) {
        const int oc = oi * 16 + l15;
#pragma unroll
        for (int j = 0; j < 4; ++j) {
          const int s = q0 + quad * 4 + j;
          O[((size_t)(b * S_LEN + s)) * DMODEL + h * 128 + oc] =
              f2bf(oacc[oi][j] * inv[j]);
        }
      }
    }
  }
}

// ---------------------------------------------------------------------------
extern "C" void kernel_launch(void* const* d_in, const int* in_sizes, int n_in,
                              void* d_out, int out_size, void* d_ws,
                              size_t ws_size, hipStream_t stream) {
  const float* x  = (const float*)d_in[0];
  const float* Wq = (const float*)d_in[1];
  const float* bq = (const float*)d_in[2];
  const float* Wk = (const float*)d_in[3];
  const float* bk = (const float*)d_in[4];
  const float* Wv = (const float*)d_in[5];
  const float* bv = (const float*)d_in[6];
  const float* Wd = (const float*)d_in[7];
  const float* bd = (const float*)d_in[8];

  float* out   = (float*)d_out;
  float* a_out = out;                     // [B,S,D] fp32 (written last)
  float* k_out = out + A_ELEMS;           // present[0] fp32 [B,H,S,hd]
  float* v_out = out + 2 * A_ELEMS;       // present[1] fp32 [B,H,S,hd]
  ushort_t* ob  = (ushort_t*)d_out;
  ushort_t* xb   = ob;                    // bf16 x, a-region bytes [0,16.78M)
  ushort_t* q_ws = ob + A_ELEMS;          // bf16 q, a-region bytes [16.78M,33.55M)

  ushort_t* ws  = (ushort_t*)d_ws;        // 83.9 MB used
  ushort_t* wtq = ws;
  ushort_t* wtk = ws + W_ELEMS;
  ushort_t* wtv = ws + 2 * (size_t)W_ELEMS;
  ushort_t* wtd = ws + 3 * (size_t)W_ELEMS;
  ushort_t* attn_ws = ws + 4 * (size_t)W_ELEMS;            // bf16 [B,S,D]
  ushort_t* kb_ws   = attn_ws + (size_t)A_ELEMS;           // bf16 [B,H,S,hd]
  ushort_t* vt_ws   = attn_ws + 2 * (size_t)A_ELEMS;       // bf16 [B,H,hd,S]

  conv_x<<<4096, 256, 0, stream>>>(x, xb);
  trans_w<<<dim3(32, 32, 4), 256, 0, stream>>>(Wq, Wk, Wv, Wd,
                                               wtq, wtk, wtv, wtd);
  gemm_qkv<<<1536, 256, 0, stream>>>(xb, wtq, wtk, wtv, bq, bk, bv,
                                     q_ws, k_out, v_out, kb_ws);
  trans_v<<<dim3(32, 2, 32), 256, 0, stream>>>(v_out, vt_ws);
  attn_fwd<<<256, 512, 0, stream>>>(q_ws, kb_ws, vt_ws, attn_ws);
  gemm_proj<<<512, 256, 0, stream>>>(attn_ws, wtd, bd, a_out);
}

// Round 2
// 445.227 us; speedup vs baseline: 1.1762x; 1.0220x over previous
//
#include <hip/hip_runtime.h>

// Attention_25855703122265: B=2, S=2048, D=2048, H=16, hd=128, causal prefill.
// fp32 I/O; bf16 MFMA compute.
//
// Round 7 (this round):
//  - GEMMs rewritten to the 8-phase counted-vmcnt template (T2+T3+T4+T5):
//    256x128 tile, BK=64, 512 thr (8 waves, 2Mx4N), K-half double buffer
//    (96KB LDS), per phase {10 ds_read_b128 | 3 gld16 | barrier | 16 MFMA
//    in setprio | barrier}, vmcnt(3) once per K-tile (never 0 in loop).
//    16B-slot XOR swizzle (slot ^= (row>>1)&3) on both stage-source and
//    ds_read side. QKV = 768 blocks (3 exact CU rounds), proj = 256.
//  - attn_fwd v3 unchanged from round 6.
//
// Memory map:
//  d_out (fp32): a [0,8.39M) | k present [8.39M,16.78M) | v [16.78M,25.17M)
//    a-region reused as scratch until proj: xb bf16 @ bytes [0,16.78M),
//    q bf16 @ bytes [16.78M,33.55M)  (dead before proj GEMM writes a).
//  d_ws (83.9 MB): wt_q|wt_k|wt_v|wt_d (bf16 [N,K], 8.39MB each)
//    | attn_ws bf16 16.78MB | kb_ws bf16 16.78MB | vt_ws bf16 16.78MB

typedef unsigned short ushort_t;
typedef __attribute__((ext_vector_type(8))) short short8;   // 8 x bf16
typedef __attribute__((ext_vector_type(4))) float f32x4;

#define MFMA16x16x32 __builtin_amdgcn_mfma_f32_16x16x32_bf16
#define S_LEN   2048
#define DMODEL  2048
#define A_ELEMS 8388608   // B*S*D
#define W_ELEMS 4194304   // D*D

__device__ __forceinline__ ushort_t f2bf(float x) {
  unsigned u = __float_as_uint(x);
  u += 0x7FFFu + ((u >> 16) & 1u);
  return (ushort_t)(u >> 16);
}
__device__ __forceinline__ unsigned pack2(float lo, float hi) {
  return (unsigned)f2bf(lo) | ((unsigned)f2bf(hi) << 16);
}
struct f8 { float v[8]; };
__device__ __forceinline__ f8 ld8f(const float* p) {
  f8 r;
  float4 a = *(const float4*)p, b = *(const float4*)(p + 4);
  r.v[0]=a.x; r.v[1]=a.y; r.v[2]=a.z; r.v[3]=a.w;
  r.v[4]=b.x; r.v[5]=b.y; r.v[6]=b.z; r.v[7]=b.w;
  return r;
}
__device__ __forceinline__ uint4 cvt8(const f8& f) {
  uint4 o;
  o.x = pack2(f.v[0], f.v[1]); o.y = pack2(f.v[2], f.v[3]);
  o.z = pack2(f.v[4], f.v[5]); o.w = pack2(f.v[6], f.v[7]);
  return o;
}

// async global->LDS, 16B/lane; dest = wave-uniform base + lane*16
typedef const __attribute__((address_space(1))) void* gas_t;
typedef __attribute__((address_space(3))) void* las_t;
__device__ __forceinline__ void gld16(const void* g, void* l) {
  __builtin_amdgcn_global_load_lds((gas_t)(unsigned long long)g,
                                   (las_t)(unsigned)(unsigned long long)l,
                                   16, 0, 0);
}

// ---------------------------------------------------------------------------
// Prepass 1: x fp32 -> xb bf16 (straight convert, 8 elems/thread)
// ---------------------------------------------------------------------------
__global__ void __launch_bounds__(256) conv_x(const float* __restrict__ x,
                                              ushort_t* __restrict__ xb) {
  const int i = (blockIdx.x * 256 + threadIdx.x) * 8;
  f8 v = ld8f(x + i);
  *(uint4*)&xb[i] = cvt8(v);
}

// ---------------------------------------------------------------------------
// Prepass 2: W fp32 [K,N] -> wt bf16 [N,K]; 64x64 tiles; z picks weight
// ---------------------------------------------------------------------------
__global__ void __launch_bounds__(256) trans_w(
    const float* __restrict__ w0, const float* __restrict__ w1,
    const float* __restrict__ w2, const float* __restrict__ w3,
    ushort_t* __restrict__ o0, ushort_t* __restrict__ o1,
    ushort_t* __restrict__ o2, ushort_t* __restrict__ o3) {
  __shared__ float t[64][65];
  const float* src; ushort_t* dst;
  switch (blockIdx.z) {
    case 0: src = w0; dst = o0; break;
    case 1: src = w1; dst = o1; break;
    case 2: src = w2; dst = o2; break;
    default: src = w3; dst = o3; break;
  }
  const int kb = blockIdx.y * 64, nb = blockIdx.x * 64;
  const int r = threadIdx.x >> 3, c8 = (threadIdx.x & 7) * 8;
#pragma unroll
  for (int i = 0; i < 64; i += 32) {
    *(float4*)&t[r + i][c8]     = *(const float4*)&src[(size_t)(kb + r + i) * DMODEL + nb + c8];
    *(float4*)&t[r + i][c8 + 4] = *(const float4*)&src[(size_t)(kb + r + i) * DMODEL + nb + c8 + 4];
  }
  __syncthreads();
#pragma unroll
  for (int i = 0; i < 64; i += 32) {
    float tmp[8];
#pragma unroll
    for (int j = 0; j < 8; ++j) tmp[j] = t[c8 + j][r + i];
    uint4 o;
    o.x = pack2(tmp[0], tmp[1]); o.y = pack2(tmp[2], tmp[3]);
    o.z = pack2(tmp[4], tmp[5]); o.w = pack2(tmp[6], tmp[7]);
    *(uint4*)&dst[(size_t)(nb + r + i) * DMODEL + kb + c8] = o;
  }
}

// ---------------------------------------------------------------------------
// Prepass 3 (after gemm_qkv): v fp32 [B,H,S,128] -> vt bf16 [B,H,128,S]
// ---------------------------------------------------------------------------
__global__ void __launch_bounds__(256) trans_v(const float* __restrict__ v,
                                               ushort_t* __restrict__ vt) {
  __shared__ float t[64][65];
  const int bh = blockIdx.z;
  const int sb = blockIdx.x * 64, db = blockIdx.y * 64;
  const float* src = v + (size_t)bh * S_LEN * 128;
  ushort_t* dst = vt + (size_t)bh * 128 * S_LEN;
  const int r = threadIdx.x >> 3, c8 = (threadIdx.x & 7) * 8;
#pragma unroll
  for (int i = 0; i < 64; i += 32) {
    *(float4*)&t[r + i][c8]     = *(const float4*)&src[(size_t)(sb + r + i) * 128 + db + c8];
    *(float4*)&t[r + i][c8 + 4] = *(const float4*)&src[(size_t)(sb + r + i) * 128 + db + c8 + 4];
  }
  __syncthreads();
#pragma unroll
  for (int i = 0; i < 64; i += 32) {
    float tmp[8];
#pragma unroll
    for (int j = 0; j < 8; ++j) tmp[j] = t[c8 + j][r + i];
    uint4 o;
    o.x = pack2(tmp[0], tmp[1]); o.y = pack2(tmp[2], tmp[3]);
    o.z = pack2(tmp[4], tmp[5]); o.w = pack2(tmp[6], tmp[7]);
    *(uint4*)&dst[(size_t)(db + r + i) * S_LEN + sb + c8] = o;
  }
}

// ---------------------------------------------------------------------------
// 8-phase GEMM core (T2+T3+T4+T5).  C[256,128] tile, BK=64 in two k-halves.
// LDS: A[2buf][2half][256][32] (64KB) + B[2buf][2half][128][32] (32KB).
// Swizzle: 16B slot s stored at s ^ ((row>>1)&3), both sides.
// Per phase: 10 ds_read_b128 + 3 gld16 + barrier + 16 MFMA (setprio) + barrier.
// vmcnt(3) once per K-tile at ph1 end: drains next tile's 6 stage loads,
// leaves the 3 newest (tile t+2 k0) in flight.  nt = 2048/64 = 32.
// ---------------------------------------------------------------------------
#define BUFA (2 * 256 * 32)   // elems per A buf (one double-buffer slot)
#define BUFB (2 * 128 * 32)

__device__ __forceinline__ void stage3(
    const ushort_t* __restrict__ gA, const ushort_t* __restrict__ gB,
    ushort_t* Ab, ushort_t* Bb, int tile, int ks, int w, size_t a_off) {
  const size_t kc = (size_t)(tile * 64 + ks * 32);
  gld16(gA + (size_t)(w * 16) * 2048 + kc + a_off,
        Ab + (ks * 256 + w * 16) * 32);
  gld16(gA + (size_t)((w + 8) * 16) * 2048 + kc + a_off,
        Ab + (ks * 256 + (w + 8) * 16) * 32);
  gld16(gB + (size_t)(w * 16) * 2048 + kc + a_off,
        Bb + (ks * 128 + w * 16) * 32);
}

__device__ __forceinline__ void gemm8p_core(
    const ushort_t* __restrict__ gA, const ushort_t* __restrict__ gB,
    ushort_t* AsF, ushort_t* BsF, int w, int lane, f32x4 acc[8][2]) {
  const int l15 = lane & 15, quad = lane >> 4;
  const int wm = w >> 2, wn = w & 3;
  // staging lane geometry: row-in-chunk = lane>>2, slot = lane&3,
  // pre-swizzled source slot = slot ^ ((lds_row>>1)&3) = (lane&3)^((lane>>3)&3)
  const size_t a_off = (size_t)(lane >> 2) * 2048 +
                       (((lane & 3) ^ ((lane >> 3) & 3)) * 8);
  // read-side swizzled slot: (quad ^ ((row>>1)&3))*8, row>>1&3 == (l15>>1)&3
  const int rslot8 = (quad ^ ((l15 >> 1) & 3)) * 8;
  const int arow = wm * 128 + l15;   // + mi*16
  const int brow = wn * 32 + l15;    // + ni*16

  // prologue: t0k0, t0k1 (buf0), t1k0 (buf1) = 9 loads; drain to 3.
  stage3(gA, gB, AsF, BsF, 0, 0, w, a_off);
  stage3(gA, gB, AsF, BsF, 0, 1, w, a_off);
  stage3(gA, gB, AsF + BUFA, BsF + BUFB, 1, 0, w, a_off);
  asm volatile("s_waitcnt vmcnt(3)" ::: "memory");
  asm volatile("s_barrier" ::: "memory");

  for (int t = 0; t < 32; ++t) {
    ushort_t* Ab  = AsF + (t & 1) * BUFA;
    ushort_t* Bb  = BsF + (t & 1) * BUFB;
    ushort_t* Abn = AsF + ((t + 1) & 1) * BUFA;
    ushort_t* Bbn = BsF + ((t + 1) & 1) * BUFB;
    short8 af[8], bf[2];
    // ---- phase 0 (k-half 0) ----
#pragma unroll
    for (int mi = 0; mi < 8; ++mi)
      af[mi] = *(const short8*)&Ab[(arow + mi * 16) * 32 + rslot8];
#pragma unroll
    for (int ni = 0; ni < 2; ++ni)
      bf[ni] = *(const short8*)&Bb[(brow + ni * 16) * 32 + rslot8];
    if (t + 1 < 32) stage3(gA, gB, Abn, Bbn, t + 1, 1, w, a_off);
    asm volatile("s_barrier" ::: "memory");
    __builtin_amdgcn_s_setprio(1);
#pragma unroll
    for (int mi = 0; mi < 8; ++mi)
#pragma unroll
      for (int ni = 0; ni < 2; ++ni)
        acc[mi][ni] = MFMA16x16x32(af[mi], bf[ni], acc[mi][ni], 0, 0, 0);
    __builtin_amdgcn_s_setprio(0);
    asm volatile("s_barrier" ::: "memory");
    // ---- phase 1 (k-half 1) ----
#pragma unroll
    for (int mi = 0; mi < 8; ++mi)
      af[mi] = *(const short8*)&Ab[(256 * 32) + (arow + mi * 16) * 32 + rslot8];
#pragma unroll
    for (int ni = 0; ni < 2; ++ni)
      bf[ni] = *(const short8*)&Bb[(128 * 32) + (brow + ni * 16) * 32 + rslot8];
    if (t + 2 < 32) stage3(gA, gB, Ab, Bb, t + 2, 0, w, a_off);
    asm volatile("s_barrier" ::: "memory");
    __builtin_amdgcn_s_setprio(1);
#pragma unroll
    for (int mi = 0; mi < 8; ++mi)
#pragma unroll
      for (int ni = 0; ni < 2; ++ni)
        acc[mi][ni] = MFMA16x16x32(af[mi], bf[ni], acc[mi][ni], 0, 0, 0);
    __builtin_amdgcn_s_setprio(0);
    if (t < 30)       asm volatile("s_waitcnt vmcnt(3)" ::: "memory");
    else if (t == 30) asm volatile("s_waitcnt vmcnt(0)" ::: "memory");
    asm volatile("s_barrier" ::: "memory");
  }
}

// ---------------------------------------------------------------------------
// Fused QKV GEMM (8-phase core).  768 blocks: wid = bx>>8 picks {q,k,v};
// idx = bx&255: tm = idx&15 (256-row tile), tn = idx>>4 (128-col tile).
// ---------------------------------------------------------------------------
__global__ void __launch_bounds__(512, 2) gemm_qkv(
    const ushort_t* __restrict__ xb,
    const ushort_t* __restrict__ wtq, const ushort_t* __restrict__ wtk,
    const ushort_t* __restrict__ wtv,
    const float* __restrict__ bq, const float* __restrict__ bk,
    const float* __restrict__ bv,
    ushort_t* __restrict__ qout, float* __restrict__ kout,
    float* __restrict__ vout, ushort_t* __restrict__ kb16) {
  __shared__ ushort_t As_[2 * BUFA];   // 64KB
  __shared__ ushort_t Bs_[2 * BUFB];   // 32KB
  const int tid = threadIdx.x, w = tid >> 6, lane = tid & 63;
  const int l15 = lane & 15, quad = lane >> 4;
  const int wm = w >> 2, wn = w & 3;
  const int bx = blockIdx.x, wid = bx >> 8, idx = bx & 255;
  const int tm = idx & 15, tn = idx >> 4;
  const ushort_t* Wt = wid == 0 ? wtq : (wid == 1 ? wtk : wtv);
  const float* bias = wid == 0 ? bq : (wid == 1 ? bk : bv);

  f32x4 acc[8][2] = {};
  gemm8p_core(xb + (size_t)(tm * 256) * 2048, Wt + (size_t)(tn * 128) * 2048,
              As_, Bs_, w, lane, acc);

  const int row0 = tm * 256 + wm * 128, col0 = tn * 128 + wn * 32;
#pragma unroll
  for (int ni = 0; ni < 2; ++ni) {
    const int col = col0 + ni * 16 + l15;
    const float bv_ = bias[col];
    const int h = col >> 7, d = col & 127;
#pragma unroll
    for (int mi = 0; mi < 8; ++mi) {
#pragma unroll
      for (int j = 0; j < 4; ++j) {
        const int row = row0 + mi * 16 + quad * 4 + j;
        const int b = row >> 11, s = row & 2047;
        const size_t idxg = (size_t)(((b * 16 + h) * 2048 + s)) * 128 + d;
        const float v = acc[mi][ni][j] + bv_;
        if (wid == 0) qout[idxg] = f2bf(v);
        else if (wid == 1) { kout[idxg] = v; kb16[idxg] = f2bf(v); }
        else vout[idxg] = v;
      }
    }
  }
}

// ---------------------------------------------------------------------------
// Proj GEMM (8-phase core): a[4096,2048] fp32 = attn_ws bf16 @ wt_d^T + bd
// 256 blocks: tm = bx&15, tn = bx>>4.
// ---------------------------------------------------------------------------
__global__ void __launch_bounds__(512, 2) gemm_proj(
    const ushort_t* __restrict__ A, const ushort_t* __restrict__ Wt,
    const float* __restrict__ bias, float* __restrict__ C) {
  __shared__ ushort_t As_[2 * BUFA];
  __shared__ ushort_t Bs_[2 * BUFB];
  const int tid = threadIdx.x, w = tid >> 6, lane = tid & 63;
  const int l15 = lane & 15, quad = lane >> 4;
  const int wm = w >> 2, wn = w & 3;
  const int tm = blockIdx.x & 15, tn = blockIdx.x >> 4;

  f32x4 acc[8][2] = {};
  gemm8p_core(A + (size_t)(tm * 256) * 2048, Wt + (size_t)(tn * 128) * 2048,
              As_, Bs_, w, lane, acc);

  const int row0 = tm * 256 + wm * 128, col0 = tn * 128 + wn * 32;
#pragma unroll
  for (int ni = 0; ni < 2; ++ni) {
    const int col = col0 + ni * 16 + l15;
    const float bv_ = bias[col];
#pragma unroll
    for (int mi = 0; mi < 8; ++mi)
#pragma unroll
      for (int j = 0; j < 4; ++j) {
        const int row = row0 + mi * 16 + quad * 4 + j;
        C[(size_t)row * DMODEL + col] = acc[mi][ni][j] + bv_;
      }
  }
}

// ---------------------------------------------------------------------------
// Flash causal attention v3 (unchanged from round 6).
// ---------------------------------------------------------------------------
__global__ void __launch_bounds__(512, 2) attn_fwd(
    const ushort_t* __restrict__ Q, const ushort_t* __restrict__ Kb,
    const ushort_t* __restrict__ Vt, ushort_t* __restrict__ O) {
  __shared__ ushort_t KP[128 * 136];  // K tile [key][d] (linear 128x128) / Ps
  __shared__ ushort_t Vs[128 * 128];  // V^T tile [d][key] (linear, swizzled)
  const int tid = threadIdx.x;
  const int w = tid >> 6, lane = tid & 63;
  const int l15 = lane & 15, quad = lane >> 4;
  const int x7 = l15 & 7;                   // read-side swizzle term
  const int bh = blockIdx.x & 31, pr = blockIdx.x >> 5;
  const int b = bh >> 4, h = bh & 15;
  const size_t base  = (size_t)bh * (S_LEN * 128);  // Q,Kb: [bh][s][128]
  const size_t vbase = (size_t)bh * (128 * S_LEN);  // Vt:   [bh][d][s]
  const float cs = 0.08838834764831845f * 1.4426950408889634f;  // 1/sqrt(128)*log2(e)

  const int srow = lane >> 4;     // staging: row within 4-row group
  const int schunk = lane & 15;   // staging: 16B slot within 256B row

  for (int seg = 0; seg < 2; ++seg) {
    const int qt = (seg == 0) ? (15 - pr) : pr;
    const int q0 = qt * 128 + w * 16;   // this wave's first q row

    // Q fragments: A-layout A[m=l15][k=quad*8+j]
    short8 qf[4];
#pragma unroll
    for (int ks = 0; ks < 4; ++ks)
      qf[ks] = *(const short8*)&Q[base + (size_t)(q0 + l15) * 128 + ks * 32 + quad * 8];

    f32x4 oacc[8] = {};
    float mrun[4], lrun[4];
#pragma unroll
    for (int j = 0; j < 4; ++j) { mrun[j] = -1e30f; lrun[j] = 0.f; }

    for (int kt = 0; kt <= qt; ++kt) {
      const int kb_ = kt * 128;
      __syncthreads();  // prev iter's Ps/Vs reads done; buffers free
#pragma unroll
      for (int i = 0; i < 4; ++i) {
        const int r = w * 16 + i * 4 + srow;
        const int c = schunk ^ (r & 7);           // pre-swizzled source chunk
        gld16(Kb + base + (size_t)(kb_ + r) * 128 + c * 8,
              (void*)(KP + (w * 16 + i * 4) * 128));
        gld16(Vt + vbase + (size_t)r * S_LEN + kb_ + c * 8,
              (void*)(Vs + (w * 16 + i * 4) * 128));
      }
      __syncthreads();  // drains vmcnt; staged data ready

      // S = Q K^T over 128 keys
      f32x4 sacc[8] = {};
#pragma unroll
      for (int ks = 0; ks < 4; ++ks) {
        const int sw = ((ks * 4 + quad) ^ x7) * 8;  // swizzled chunk offset
        short8 kf[8];
#pragma unroll
        for (int ni = 0; ni < 8; ++ni)
          kf[ni] = *(const short8*)&KP[(ni * 16 + l15) * 128 + sw];
#pragma unroll
        for (int ni = 0; ni < 8; ++ni)
          sacc[ni] = MFMA16x16x32(qf[ks], kf[ni], sacc[ni], 0, 0, 0);
      }
      __syncthreads();  // all kf reads done; KP becomes Ps [128][136]

      // online softmax: lane holds rows quad*4+j, cols ni*16+l15
#pragma unroll
      for (int j = 0; j < 4; ++j) {
        const int rl = quad * 4 + j;
        const int rowg = q0 + rl;
        float t0[8];
#pragma unroll
        for (int ni = 0; ni < 8; ++ni) {
          const int kg = kb_ + ni * 16 + l15;
          const float s = sacc[ni][j] * cs;
          t0[ni] = (kg <= rowg) ? s : -1e30f;
        }
        float rm = fmaxf(fmaxf(fmaxf(t0[0], t0[1]), fmaxf(t0[2], t0[3])),
                         fmaxf(fmaxf(t0[4], t0[5]), fmaxf(t0[6], t0[7])));
        rm = fmaxf(rm, __shfl_xor(rm, 1));
        rm = fmaxf(rm, __shfl_xor(rm, 2));
        rm = fmaxf(rm, __shfl_xor(rm, 4));
        rm = fmaxf(rm, __shfl_xor(rm, 8));
        const float mold = mrun[j];
        const float mnew = fmaxf(mold, rm);
        const float alpha = __builtin_amdgcn_exp2f(mold - mnew);
        float rs = 0.f;
#pragma unroll
        for (int ni = 0; ni < 8; ++ni) {
          const float pe = __builtin_amdgcn_exp2f(t0[ni] - mnew);
          rs += pe;
          KP[(w * 16 + rl) * 136 + ni * 16 + l15] = f2bf(pe);  // Ps
        }
        rs += __shfl_xor(rs, 1);
        rs += __shfl_xor(rs, 2);
        rs += __shfl_xor(rs, 4);
        rs += __shfl_xor(rs, 8);
        lrun[j] = lrun[j] * alpha + rs;
        mrun[j] = mnew;
#pragma unroll
        for (int oi = 0; oi < 8; ++oi) oacc[oi][j] *= alpha;
      }

      // O += P V  (Ps rows wave-private -> no barrier; Vs valid till next stage)
#pragma unroll
      for (int ks = 0; ks < 4; ++ks) {
        const int sw = ((ks * 4 + quad) ^ x7) * 8;
        short8 pf = *(const short8*)&KP[(w * 16 + l15) * 136 + ks * 32 + quad * 8];
        short8 vf[8];
#pragma unroll
        for (int oi = 0; oi < 8; ++oi)
          vf[oi] = *(const short8*)&Vs[(oi * 16 + l15) * 128 + sw];
#pragma unroll
        for (int oi = 0; oi < 8; ++oi)
          oacc[oi] = MFMA16x16x32(pf, vf[oi], oacc[oi], 0, 0, 0);
      }
    }

    // epilogue: O /= l, write merged-heads bf16 [B,S,D]
    {
      float inv[4];
#pragma unroll
      for (int j = 0; j < 4; ++j) inv[j] = 1.f / lrun[j];
#pragma unroll
      for (int oi = 0; oi < 8; ++oi) {
        const int oc = oi * 16 + l15;
#pragma unroll
        for (int j = 0; j < 4; ++j) {
          const int s = q0 + quad * 4 + j;
          O[((size_t)(b * S_LEN + s)) * DMODEL + h * 128 + oc] =
              f2bf(oacc[oi][j] * inv[j]);
        }
      }
    }
  }
}

// ---------------------------------------------------------------------------
extern "C" void kernel_launch(void* const* d_in, const int* in_sizes, int n_in,
                              void* d_out, int out_size, void* d_ws,
                              size_t ws_size, hipStream_t stream) {
  const float* x  = (const float*)d_in[0];
  const float* Wq = (const float*)d_in[1];
  const float* bq = (const float*)d_in[2];
  const float* Wk = (const float*)d_in[3];
  const float* bk = (const float*)d_in[4];
  const float* Wv = (const float*)d_in[5];
  const float* bv = (const float*)d_in[6];
  const float* Wd = (const float*)d_in[7];
  const float* bd = (const float*)d_in[8];

  float* out   = (float*)d_out;
  float* a_out = out;                     // [B,S,D] fp32 (written last)
  float* k_out = out + A_ELEMS;           // present[0] fp32 [B,H,S,hd]
  float* v_out = out + 2 * A_ELEMS;       // present[1] fp32 [B,H,S,hd]
  ushort_t* ob  = (ushort_t*)d_out;
  ushort_t* xb   = ob;                    // bf16 x, a-region bytes [0,16.78M)
  ushort_t* q_ws = ob + A_ELEMS;          // bf16 q, a-region bytes [16.78M,33.55M)

  ushort_t* ws  = (ushort_t*)d_ws;        // 83.9 MB used
  ushort_t* wtq = ws;
  ushort_t* wtk = ws + W_ELEMS;
  ushort_t* wtv = ws + 2 * (size_t)W_ELEMS;
  ushort_t* wtd = ws + 3 * (size_t)W_ELEMS;
  ushort_t* attn_ws = ws + 4 * (size_t)W_ELEMS;            // bf16 [B,S,D]
  ushort_t* kb_ws   = attn_ws + (size_t)A_ELEMS;           // bf16 [B,H,S,hd]
  ushort_t* vt_ws   = attn_ws + 2 * (size_t)A_ELEMS;       // bf16 [B,H,hd,S]

  conv_x<<<4096, 256, 0, stream>>>(x, xb);
  trans_w<<<dim3(32, 32, 4), 256, 0, stream>>>(Wq, Wk, Wv, Wd,
                                               wtq, wtk, wtv, wtd);
  gemm_qkv<<<768, 512, 0, stream>>>(xb, wtq, wtk, wtv, bq, bk, bv,
                                    q_ws, k_out, v_out, kb_ws);
  trans_v<<<dim3(32, 2, 32), 256, 0, stream>>>(v_out, vt_ws);
  attn_fwd<<<256, 512, 0, stream>>>(q_ws, kb_ws, vt_ws, attn_ws);
  gemm_proj<<<256, 512, 0, stream>>>(attn_ws, wtd, bd, a_out);
}